// Round 5
// baseline (469.582 us; speedup 1.0000x reference)
//
#include <hip/hip_runtime.h>
#include <math.h>

// LatentGraphNetwork: out = LN(GELU(x @ W_eff + b_eff) @ W_out + b_out)
//   W_eff = W_upd[:128] + (W_msg@graph)@W_upd[128:]   (precomputed per launch)
//   b_eff = b_upd + (b_msg@graph)@W_upd[128:]
// B=64, T=4096, D=128 -> 262144 rows of 128 fp32.
//
// R5: transposed dataflow (HW-verified, absmax 0.047): both GEMMs with
// swapped MFMA operands; GEMM2 fragments via ds_bpermute lane exchange.
// No per-tile barriers. LDS 66 KB.
// R7: plain __launch_bounds__(512) -> VGPR=128, but still ~730 MB scratch
// traffic (FETCH +447/WRITE +258 MB): peak arch-VGPR demand slightly >128
// because the xn prefetch (32 regs) stays live through GEMM1 while the
// unrolled bpermute batch holds ~48 more. Occupancy 22% (unified VGPR+ACC
// file: 128+acc ~= 2 waves/SIMD).
// R8: remove the xn prefetch entirely; load+convert x at tile top;
// #pragma unroll 1 on the tile loop so the compiler cannot re-hoist
// next-tile loads. Peak live ~70 VGPR + 32 acc -> ~110 total -> 4 waves/
// SIMD (16/CU, the LDS cap), zero spill. Latency hidden by TLP, not ILP.
// (R8 submission failed on container acquisition — resubmitted unchanged.)

#define D 128
#define NROWS (64 * 4096)

typedef __bf16 bf16x8 __attribute__((ext_vector_type(8)));
typedef __bf16 bf16x2 __attribute__((ext_vector_type(2)));
typedef float  f32x4  __attribute__((ext_vector_type(4)));
typedef int    i32x4  __attribute__((ext_vector_type(4)));

// swizzled element index for a 128x128 bf16 matrix stored for conflict-free
// ds_read_b128 fragments: element (o, i) -> o*128 + (((i>>3) ^ (o&15))<<3) + (i&7)
__device__ __forceinline__ int wswz(int o, int i) {
    return o * 128 + ((((i >> 3) ^ (o & 15)) & 15) << 3) + (i & 7);
}

// ---------------- prelude 1: G2 = W_msg@graph, b2tmp = b_msg@graph, W2s = swizzled W_out^T (bf16)
__global__ __launch_bounds__(256) void prep1(
    const float* __restrict__ W_msg, const float* __restrict__ graph,
    const float* __restrict__ b_msg, const float* __restrict__ W_out,
    float* __restrict__ G2, float* __restrict__ b2tmp, __bf16* __restrict__ W2s) {
    __shared__ float gs[D * D];  // 64 KB
    const int tid = threadIdx.x;
    {
        const float4* g4 = (const float4*)graph;
        float4* s4 = (float4*)gs;
#pragma unroll
        for (int it = 0; it < (D * D / 4) / 256; ++it)
            s4[tid + it * 256] = g4[tid + it * 256];
    }
    __syncthreads();
    const int i0 = blockIdx.x * 8;
#pragma unroll
    for (int p = 0; p < 4; ++p) {
        const int flat = tid + p * 256;
        const int i = i0 + (flat >> 7);   // row of W_out / W_msg
        const int g = flat & 127;         // col
        const float* wrow = W_msg + i * D;
        float s = 0.f;
#pragma unroll 8
        for (int h = 0; h < D; ++h) s += wrow[h] * gs[h * D + g];
        G2[i * D + g] = s;
        // W2t element (o=g, k=i), swizzled
        W2s[wswz(g, i)] = (__bf16)W_out[i * D + g];
    }
    if (blockIdx.x == 0 && tid < 128) {
        float sb = 0.f;
#pragma unroll 8
        for (int h = 0; h < D; ++h) sb += b_msg[h] * gs[h * D + tid];
        b2tmp[tid] = sb;
    }
}

// ---------------- prelude 2: W1s = swizzled W_eff^T (bf16), b_eff
__global__ __launch_bounds__(256) void prep2(
    const float* __restrict__ W_upd, const float* __restrict__ b_upd,
    const float* __restrict__ G2, const float* __restrict__ b2tmp,
    __bf16* __restrict__ W1s, float* __restrict__ b_eff) {
    __shared__ float wls[D * D];  // W_upd rows 128..255
    const int tid = threadIdx.x;
    {
        const float4* w4 = (const float4*)(W_upd + D * D);
        float4* s4 = (float4*)wls;
#pragma unroll
        for (int it = 0; it < (D * D / 4) / 256; ++it)
            s4[tid + it * 256] = w4[tid + it * 256];
    }
    __syncthreads();
    const int i0 = blockIdx.x * 8;
#pragma unroll
    for (int p = 0; p < 4; ++p) {
        const int flat = tid + p * 256;
        const int i = i0 + (flat >> 7);   // input dim
        const int o = flat & 127;         // output dim
        const float* g2row = G2 + i * D;
        float s = W_upd[i * D + o];
#pragma unroll 8
        for (int g = 0; g < D; ++g) s += g2row[g] * wls[g * D + o];
        W1s[wswz(o, i)] = (__bf16)s;
    }
    if (blockIdx.x == 0 && tid < 128) {
        float sb = b_upd[tid];
#pragma unroll 8
        for (int g = 0; g < D; ++g) sb += b2tmp[g] * wls[g * D + tid];
        b_eff[tid] = sb;
    }
}

// fast GELU: v * sigmoid(2*sqrt(2/pi)*(v + 0.044715 v^3)); max abs err ~1e-3
__device__ __forceinline__ float gelu_fast(float v) {
    const float u = 1.5957691216057308f * v * (1.0f + 0.044715f * v * v);
    return v / (1.0f + __expf(-u));
}

__device__ __forceinline__ uint32_t pkbf16(float x, float y) {
    bf16x2 p;
    p[0] = (__bf16)x;
    p[1] = (__bf16)y;
    return __builtin_bit_cast(uint32_t, p);
}

// ---------------- fused main (transposed dataflow, barrier-free tile loop)
//
// Fragment bookkeeping (wave lane l: q = l>>4, m = l&15):
//  GEMM1^T: acc[t] = mfma(Wf, xf): lane holds H^T[o = t*16+q*4+j][row = m]
//           = H[rowbase+m][c], c = t*16+q*4+j  (4 contiguous c per t)
//  GEMM2 B-frag needs Hg[m][c = ks*32 + q*8 + d], d=0..7. Source holder of
//  (m, c): lane (q' = (c>>2)&3, m), acc-index t' = c>>4 = 2ks + (q>>1),
//  j' = c&3. So: srcA lane = ((2q)&3)*16+m supplies d=0..3, srcB = srcA+16
//  supplies d=4..7; register select lo/hi[2ks] vs [2ks+1] by (q>>1).
//  Hand-verified AND harness-verified (R5/R6/R7 passed, absmax 0.046875).
__global__ __launch_bounds__(512) void fused_main(
    const float* __restrict__ x, const __bf16* __restrict__ Wsrc,  // [W1s|W2s] 64KB
    const float* __restrict__ b1, const float* __restrict__ b2,
    const float* __restrict__ gamma, const float* __restrict__ beta,
    float* __restrict__ out) {

    __shared__ __align__(16) __bf16 Wlds[2 * 128 * 128];  // 64 KB: W1 @0, W2 @16384
    __shared__ __align__(16) float b1s[128];
    __shared__ __align__(16) float b2s[128];
    __shared__ __align__(16) float gms[128];
    __shared__ __align__(16) float bts[128];

    const int tid = threadIdx.x;
    // ---- stage weights (contiguous 64 KB copy; source pre-swizzled by preludes)
    {
        const float4* src4 = (const float4*)Wsrc;
        float4* dst4 = (float4*)Wlds;
#pragma unroll
        for (int it = 0; it < 8; ++it) dst4[it * 512 + tid] = src4[it * 512 + tid];
    }
    if (tid < 128) {
        b1s[tid] = b1[tid];
        b2s[tid] = b2[tid];
        gms[tid] = gamma[tid];
        bts[tid] = beta[tid];
    }

    const int w = tid >> 6;        // wave 0..7
    const int l = tid & 63;
    const int q = l >> 4;          // quad-of-16
    const int m = l & 15;

    // bpermute source-lane byte addresses (lane*4)
    const int addrA = ((((2 * q) & 3) << 4) | m) << 2;
    const int addrB = addrA + 64;
    const bool qhi = (q & 2) != 0;

    __syncthreads();  // the only block barrier: weights staged

    const int rowbase0 = blockIdx.x * 512 + w * 64;
    const float* xbase = x + (size_t)(rowbase0 + m) * D;

#pragma unroll 1
    for (int tile = 0; tile < 4; ++tile) {
        const int rowbase = rowbase0 + tile * 16;

        // ---- load this tile's x and convert to bf16 A-frags
        //      a[ks][e] = x[row m][ks*32 + q*8 + e]
        bf16x8 a[4];
        {
            const float* xrow = xbase + (size_t)tile * 16 * D;
#pragma unroll
            for (int ks = 0; ks < 4; ++ks) {
                const float4* xp = (const float4*)(xrow + ks * 32 + q * 8);
                const float4 xa = xp[0], xb = xp[1];
                a[ks][0] = (__bf16)xa.x; a[ks][1] = (__bf16)xa.y;
                a[ks][2] = (__bf16)xa.z; a[ks][3] = (__bf16)xa.w;
                a[ks][4] = (__bf16)xb.x; a[ks][5] = (__bf16)xb.y;
                a[ks][6] = (__bf16)xb.z; a[ks][7] = (__bf16)xb.w;
            }
        }

        // ---- GEMM1^T: acc[t] holds H^T (lane: o = t*16+q*4+j, row = m)
        f32x4 acc[8];
#pragma unroll
        for (int t = 0; t < 8; ++t) acc[t] = (f32x4)(0.0f);
#pragma unroll
        for (int ks = 0; ks < 4; ++ks) {
            const int blk = (((ks * 4 + q) ^ m) & 15) << 3;
#pragma unroll
            for (int t = 0; t < 8; ++t) {
                const bf16x8 wf = *(const bf16x8*)&Wlds[(t * 16 + m) * 128 + blk];
                acc[t] = __builtin_amdgcn_mfma_f32_16x16x32_bf16(wf, a[ks], acc[t], 0, 0, 0);
            }
        }

        // ---- bias + GELU -> packed bf16 pairs (lo = j0,j1; hi = j2,j3)
        uint32_t lov[8], hiv[8];
#pragma unroll
        for (int t = 0; t < 8; ++t) {
            const f32x4 bq = *(const f32x4*)&b1s[t * 16 + q * 4];
            lov[t] = pkbf16(gelu_fast(acc[t][0] + bq[0]), gelu_fast(acc[t][1] + bq[1]));
            hiv[t] = pkbf16(gelu_fast(acc[t][2] + bq[2]), gelu_fast(acc[t][3] + bq[3]));
        }

        // ---- lane-exchange H^T into GEMM2 fragments (no LDS, no barrier)
        bf16x8 hf[4];
#pragma unroll
        for (int ks = 0; ks < 4; ++ks) {
            const int l0 = (int)lov[2 * ks], l1 = (int)lov[2 * ks + 1];
            const int h0 = (int)hiv[2 * ks], h1 = (int)hiv[2 * ks + 1];
            const int w0a = __builtin_amdgcn_ds_bpermute(addrA, l0);
            const int w0b = __builtin_amdgcn_ds_bpermute(addrA, l1);
            const int w1a = __builtin_amdgcn_ds_bpermute(addrA, h0);
            const int w1b = __builtin_amdgcn_ds_bpermute(addrA, h1);
            const int w2a = __builtin_amdgcn_ds_bpermute(addrB, l0);
            const int w2b = __builtin_amdgcn_ds_bpermute(addrB, l1);
            const int w3a = __builtin_amdgcn_ds_bpermute(addrB, h0);
            const int w3b = __builtin_amdgcn_ds_bpermute(addrB, h1);
            i32x4 wv;
            wv[0] = qhi ? w0b : w0a;
            wv[1] = qhi ? w1b : w1a;
            wv[2] = qhi ? w2b : w2a;
            wv[3] = qhi ? w3b : w3a;
            hf[ks] = __builtin_bit_cast(bf16x8, wv);
        }

        // ---- GEMM2^T: acc2[t] holds O^T (lane: o2 = t*16+q*4+j, row = m)
        f32x4 acc2[8];
#pragma unroll
        for (int t = 0; t < 8; ++t) acc2[t] = (f32x4)(0.0f);
#pragma unroll
        for (int ks = 0; ks < 4; ++ks) {
            const int blk = (((ks * 4 + q) ^ m) & 15) << 3;
#pragma unroll
            for (int t = 0; t < 8; ++t) {
                const bf16x8 wf = *(const bf16x8*)&Wlds[16384 + (t * 16 + m) * 128 + blk];
                acc2[t] = __builtin_amdgcn_mfma_f32_16x16x32_bf16(wf, hf[ks], acc2[t], 0, 0, 0);
            }
        }

        // ---- + b_out, LayerNorm: row m lives in 4 lanes -> 2 shuffles
        float vs = 0.f, vq = 0.f;
#pragma unroll
        for (int t = 0; t < 8; ++t) {
            const f32x4 bq = *(const f32x4*)&b2s[t * 16 + q * 4];
#pragma unroll
            for (int j = 0; j < 4; ++j) {
                const float v = acc2[t][j] + bq[j];
                acc2[t][j] = v;
                vs += v;
                vq += v * v;
            }
        }
        vs += __shfl_xor(vs, 16);
        vq += __shfl_xor(vq, 16);
        vs += __shfl_xor(vs, 32);
        vq += __shfl_xor(vq, 32);

        const float mu = vs * (1.0f / 128.0f);
        const float var = vq * (1.0f / 128.0f) - mu * mu;
        const float rstd = rsqrtf(var + 1e-5f);
        const float nmr = -mu * rstd;

        float* orow = out + (size_t)(rowbase + m) * D;
#pragma unroll
        for (int t = 0; t < 8; ++t) {
            const f32x4 gq = *(const f32x4*)&gms[t * 16 + q * 4];
            const f32x4 bq = *(const f32x4*)&bts[t * 16 + q * 4];
            float4 res;
            res.x = fmaf(fmaf(acc2[t][0], rstd, nmr), gq[0], bq[0]);
            res.y = fmaf(fmaf(acc2[t][1], rstd, nmr), gq[1], bq[1]);
            res.z = fmaf(fmaf(acc2[t][2], rstd, nmr), gq[2], bq[2]);
            res.w = fmaf(fmaf(acc2[t][3], rstd, nmr), gq[3], bq[3]);
            *(float4*)(orow + t * 16 + q * 4) = res;
        }
    }
}

extern "C" void kernel_launch(void* const* d_in, const int* in_sizes, int n_in,
                              void* d_out, int out_size, void* d_ws, size_t ws_size,
                              hipStream_t stream) {
    const float* x     = (const float*)d_in[0];
    const float* graph = (const float*)d_in[1];
    const float* W_msg = (const float*)d_in[2];
    const float* b_msg = (const float*)d_in[3];
    const float* W_upd = (const float*)d_in[4];
    const float* b_upd = (const float*)d_in[5];
    const float* W_out = (const float*)d_in[6];
    const float* b_out = (const float*)d_in[7];
    const float* gamma = (const float*)d_in[8];
    const float* beta  = (const float*)d_in[9];
    float* out = (float*)d_out;

    char* ws = (char*)d_ws;
    __bf16* W1s   = (__bf16*)(ws + 0);       // 32768 B (swizzled bf16 W_eff^T)
    __bf16* W2s   = (__bf16*)(ws + 32768);   // 32768 B (swizzled bf16 W_out^T)
    float*  G2    = (float*)(ws + 65536);    // 65536 B
    float*  b2tmp = (float*)(ws + 131072);   // 512 B
    float*  b_eff = (float*)(ws + 131584);   // 512 B

    prep1<<<16, 256, 0, stream>>>(W_msg, graph, b_msg, W_out, G2, b2tmp, W2s);
    prep2<<<16, 256, 0, stream>>>(W_upd, b_upd, G2, b2tmp, W1s, b_eff);
    fused_main<<<NROWS / 512, 512, 0, stream>>>(x, W1s, b_eff, b_out, gamma, beta, out);
}

// Round 6
// 294.593 us; speedup vs baseline: 1.5940x; 1.5940x over previous
//
#include <hip/hip_runtime.h>
#include <math.h>

// LatentGraphNetwork: out = LN(GELU(x @ W_eff + b_eff) @ W_out + b_out)
//   W_eff = W_upd[:128] + (W_msg@graph)@W_upd[128:]   (precomputed per launch)
//   b_eff = b_upd + (b_msg@graph)@W_upd[128:]
// B=64, T=4096, D=128 -> 262144 rows of 128 fp32.
//
// R5: transposed dataflow (HW-verified, absmax 0.047): both GEMMs with
// swapped MFMA operands; GEMM2 fragments via ds_bpermute lane exchange.
// No per-tile barriers. LDS 66 KB.
// R7/R8: VGPR=128 but ~540 MB scratch traffic persisted; removing the x
// prefetch only shaved 160 MB. Diagnosis: with the per-tile barriers gone,
// LICM hoists tile-invariant LDS reads (64 weight fragments = up to 256
// regs; 128 floats of bias/gamma/beta quads) out of the tile loop, pinning
// invariants in registers and spilling the working set. R4 never spilled
// because __syncthreads() acted as a compiler memory fence blocking LICM.
//
// R9: (1) asm volatile("" ::: "memory") at the top of each tile iteration —
// a zero-cost compiler fence that keeps every LDS read inside the loop
// (R4's fence effect without R4's execution barrier). (2) Fuse
// GELU->pack->bpermute per ks (hf[ks] only needs lov/hiv[2ks,2ks+1]),
// trimming ~16 regs off the mid-tile peak. Peak live ~80-95 regs -> no
// spill at the 128 budget, 16 waves/CU (LDS cap).

#define D 128
#define NROWS (64 * 4096)

typedef __bf16 bf16x8 __attribute__((ext_vector_type(8)));
typedef __bf16 bf16x2 __attribute__((ext_vector_type(2)));
typedef float  f32x4  __attribute__((ext_vector_type(4)));
typedef int    i32x4  __attribute__((ext_vector_type(4)));

// swizzled element index for a 128x128 bf16 matrix stored for conflict-free
// ds_read_b128 fragments: element (o, i) -> o*128 + (((i>>3) ^ (o&15))<<3) + (i&7)
__device__ __forceinline__ int wswz(int o, int i) {
    return o * 128 + ((((i >> 3) ^ (o & 15)) & 15) << 3) + (i & 7);
}

// ---------------- prelude 1: G2 = W_msg@graph, b2tmp = b_msg@graph, W2s = swizzled W_out^T (bf16)
__global__ __launch_bounds__(256) void prep1(
    const float* __restrict__ W_msg, const float* __restrict__ graph,
    const float* __restrict__ b_msg, const float* __restrict__ W_out,
    float* __restrict__ G2, float* __restrict__ b2tmp, __bf16* __restrict__ W2s) {
    __shared__ float gs[D * D];  // 64 KB
    const int tid = threadIdx.x;
    {
        const float4* g4 = (const float4*)graph;
        float4* s4 = (float4*)gs;
#pragma unroll
        for (int it = 0; it < (D * D / 4) / 256; ++it)
            s4[tid + it * 256] = g4[tid + it * 256];
    }
    __syncthreads();
    const int i0 = blockIdx.x * 8;
#pragma unroll
    for (int p = 0; p < 4; ++p) {
        const int flat = tid + p * 256;
        const int i = i0 + (flat >> 7);   // row of W_out / W_msg
        const int g = flat & 127;         // col
        const float* wrow = W_msg + i * D;
        float s = 0.f;
#pragma unroll 8
        for (int h = 0; h < D; ++h) s += wrow[h] * gs[h * D + g];
        G2[i * D + g] = s;
        // W2t element (o=g, k=i), swizzled
        W2s[wswz(g, i)] = (__bf16)W_out[i * D + g];
    }
    if (blockIdx.x == 0 && tid < 128) {
        float sb = 0.f;
#pragma unroll 8
        for (int h = 0; h < D; ++h) sb += b_msg[h] * gs[h * D + tid];
        b2tmp[tid] = sb;
    }
}

// ---------------- prelude 2: W1s = swizzled W_eff^T (bf16), b_eff
__global__ __launch_bounds__(256) void prep2(
    const float* __restrict__ W_upd, const float* __restrict__ b_upd,
    const float* __restrict__ G2, const float* __restrict__ b2tmp,
    __bf16* __restrict__ W1s, float* __restrict__ b_eff) {
    __shared__ float wls[D * D];  // W_upd rows 128..255
    const int tid = threadIdx.x;
    {
        const float4* w4 = (const float4*)(W_upd + D * D);
        float4* s4 = (float4*)wls;
#pragma unroll
        for (int it = 0; it < (D * D / 4) / 256; ++it)
            s4[tid + it * 256] = w4[tid + it * 256];
    }
    __syncthreads();
    const int i0 = blockIdx.x * 8;
#pragma unroll
    for (int p = 0; p < 4; ++p) {
        const int flat = tid + p * 256;
        const int i = i0 + (flat >> 7);   // input dim
        const int o = flat & 127;         // output dim
        const float* g2row = G2 + i * D;
        float s = W_upd[i * D + o];
#pragma unroll 8
        for (int g = 0; g < D; ++g) s += g2row[g] * wls[g * D + o];
        W1s[wswz(o, i)] = (__bf16)s;
    }
    if (blockIdx.x == 0 && tid < 128) {
        float sb = b_upd[tid];
#pragma unroll 8
        for (int g = 0; g < D; ++g) sb += b2tmp[g] * wls[g * D + tid];
        b_eff[tid] = sb;
    }
}

// fast GELU: v * sigmoid(2*sqrt(2/pi)*(v + 0.044715 v^3)); max abs err ~1e-3
__device__ __forceinline__ float gelu_fast(float v) {
    const float u = 1.5957691216057308f * v * (1.0f + 0.044715f * v * v);
    return v / (1.0f + __expf(-u));
}

__device__ __forceinline__ uint32_t pkbf16(float x, float y) {
    bf16x2 p;
    p[0] = (__bf16)x;
    p[1] = (__bf16)y;
    return __builtin_bit_cast(uint32_t, p);
}

// ---------------- fused main (transposed dataflow, barrier-free tile loop)
//
// Fragment bookkeeping (wave lane l: q = l>>4, m = l&15):
//  GEMM1^T: acc[t] = mfma(Wf, xf): lane holds H^T[o = t*16+q*4+j][row = m]
//           = H[rowbase+m][c], c = t*16+q*4+j  (4 contiguous c per t)
//  GEMM2 B-frag needs Hg[m][c = ks*32 + q*8 + d], d=0..7. Source holder of
//  (m, c): lane (q' = (c>>2)&3, m), acc-index t' = c>>4 = 2ks + (q>>1),
//  j' = c&3. So: srcA lane = ((2q)&3)*16+m supplies d=0..3, srcB = srcA+16
//  supplies d=4..7; register select lo/hi[2ks] vs [2ks+1] by (q>>1).
//  Hand-verified AND harness-verified (R5/R6/R7/R8 passed, absmax 0.046875).
__global__ __launch_bounds__(512) void fused_main(
    const float* __restrict__ x, const __bf16* __restrict__ Wsrc,  // [W1s|W2s] 64KB
    const float* __restrict__ b1, const float* __restrict__ b2,
    const float* __restrict__ gamma, const float* __restrict__ beta,
    float* __restrict__ out) {

    __shared__ __align__(16) __bf16 Wlds[2 * 128 * 128];  // 64 KB: W1 @0, W2 @16384
    __shared__ __align__(16) float b1s[128];
    __shared__ __align__(16) float b2s[128];
    __shared__ __align__(16) float gms[128];
    __shared__ __align__(16) float bts[128];

    const int tid = threadIdx.x;
    // ---- stage weights (contiguous 64 KB copy; source pre-swizzled by preludes)
    {
        const float4* src4 = (const float4*)Wsrc;
        float4* dst4 = (float4*)Wlds;
#pragma unroll
        for (int it = 0; it < 8; ++it) dst4[it * 512 + tid] = src4[it * 512 + tid];
    }
    if (tid < 128) {
        b1s[tid] = b1[tid];
        b2s[tid] = b2[tid];
        gms[tid] = gamma[tid];
        bts[tid] = beta[tid];
    }

    const int w = tid >> 6;        // wave 0..7
    const int l = tid & 63;
    const int q = l >> 4;          // quad-of-16
    const int m = l & 15;

    // bpermute source-lane byte addresses (lane*4)
    const int addrA = ((((2 * q) & 3) << 4) | m) << 2;
    const int addrB = addrA + 64;
    const bool qhi = (q & 2) != 0;

    __syncthreads();  // the only block barrier: weights staged

    const int rowbase0 = blockIdx.x * 512 + w * 64;
    const float* xbase = x + (size_t)(rowbase0 + m) * D;

#pragma unroll 1
    for (int tile = 0; tile < 4; ++tile) {
        // Compiler memory fence: keeps tile-invariant LDS reads (weight
        // fragments, bias/gamma/beta quads) INSIDE the loop — blocks the
        // LICM hoisting that caused R7/R8's register spill. Emits nothing.
        asm volatile("" ::: "memory");

        const int rowbase = rowbase0 + tile * 16;

        // ---- load this tile's x and convert to bf16 A-frags
        //      a[ks][e] = x[row m][ks*32 + q*8 + e]
        bf16x8 a[4];
        {
            const float* xrow = xbase + (size_t)tile * 16 * D;
#pragma unroll
            for (int ks = 0; ks < 4; ++ks) {
                const float4* xp = (const float4*)(xrow + ks * 32 + q * 8);
                const float4 xa = xp[0], xb = xp[1];
                a[ks][0] = (__bf16)xa.x; a[ks][1] = (__bf16)xa.y;
                a[ks][2] = (__bf16)xa.z; a[ks][3] = (__bf16)xa.w;
                a[ks][4] = (__bf16)xb.x; a[ks][5] = (__bf16)xb.y;
                a[ks][6] = (__bf16)xb.z; a[ks][7] = (__bf16)xb.w;
            }
        }

        // ---- GEMM1^T: acc[t] holds H^T (lane: o = t*16+q*4+j, row = m)
        f32x4 acc[8];
#pragma unroll
        for (int t = 0; t < 8; ++t) acc[t] = (f32x4)(0.0f);
#pragma unroll
        for (int ks = 0; ks < 4; ++ks) {
            const int blk = (((ks * 4 + q) ^ m) & 15) << 3;
#pragma unroll
            for (int t = 0; t < 8; ++t) {
                const bf16x8 wf = *(const bf16x8*)&Wlds[(t * 16 + m) * 128 + blk];
                acc[t] = __builtin_amdgcn_mfma_f32_16x16x32_bf16(wf, a[ks], acc[t], 0, 0, 0);
            }
        }

        // ---- per-ks: bias + GELU + pack + lane-exchange -> hf[ks]
        //      (hf[ks] only consumes t = 2ks, 2ks+1; fusing keeps the
        //       packed words short-lived: ~16 fewer regs at peak)
        bf16x8 hf[4];
#pragma unroll
        for (int ks = 0; ks < 4; ++ks) {
            const int t0 = 2 * ks, t1 = 2 * ks + 1;
            const f32x4 bq0 = *(const f32x4*)&b1s[t0 * 16 + q * 4];
            const f32x4 bq1 = *(const f32x4*)&b1s[t1 * 16 + q * 4];
            const int l0 = (int)pkbf16(gelu_fast(acc[t0][0] + bq0[0]),
                                       gelu_fast(acc[t0][1] + bq0[1]));
            const int h0 = (int)pkbf16(gelu_fast(acc[t0][2] + bq0[2]),
                                       gelu_fast(acc[t0][3] + bq0[3]));
            const int l1 = (int)pkbf16(gelu_fast(acc[t1][0] + bq1[0]),
                                       gelu_fast(acc[t1][1] + bq1[1]));
            const int h1 = (int)pkbf16(gelu_fast(acc[t1][2] + bq1[2]),
                                       gelu_fast(acc[t1][3] + bq1[3]));
            const int w0a = __builtin_amdgcn_ds_bpermute(addrA, l0);
            const int w0b = __builtin_amdgcn_ds_bpermute(addrA, l1);
            const int w1a = __builtin_amdgcn_ds_bpermute(addrA, h0);
            const int w1b = __builtin_amdgcn_ds_bpermute(addrA, h1);
            const int w2a = __builtin_amdgcn_ds_bpermute(addrB, l0);
            const int w2b = __builtin_amdgcn_ds_bpermute(addrB, l1);
            const int w3a = __builtin_amdgcn_ds_bpermute(addrB, h0);
            const int w3b = __builtin_amdgcn_ds_bpermute(addrB, h1);
            i32x4 wv;
            wv[0] = qhi ? w0b : w0a;
            wv[1] = qhi ? w1b : w1a;
            wv[2] = qhi ? w2b : w2a;
            wv[3] = qhi ? w3b : w3a;
            hf[ks] = __builtin_bit_cast(bf16x8, wv);
        }

        // ---- GEMM2^T: acc2[t] holds O^T (lane: o2 = t*16+q*4+j, row = m)
        f32x4 acc2[8];
#pragma unroll
        for (int t = 0; t < 8; ++t) acc2[t] = (f32x4)(0.0f);
#pragma unroll
        for (int ks = 0; ks < 4; ++ks) {
            const int blk = (((ks * 4 + q) ^ m) & 15) << 3;
#pragma unroll
            for (int t = 0; t < 8; ++t) {
                const bf16x8 wf = *(const bf16x8*)&Wlds[16384 + (t * 16 + m) * 128 + blk];
                acc2[t] = __builtin_amdgcn_mfma_f32_16x16x32_bf16(wf, hf[ks], acc2[t], 0, 0, 0);
            }
        }

        // ---- + b_out, LayerNorm: row m lives in 4 lanes -> 2 shuffles
        float vs = 0.f, vq = 0.f;
#pragma unroll
        for (int t = 0; t < 8; ++t) {
            const f32x4 bq = *(const f32x4*)&b2s[t * 16 + q * 4];
#pragma unroll
            for (int j = 0; j < 4; ++j) {
                const float v = acc2[t][j] + bq[j];
                acc2[t][j] = v;
                vs += v;
                vq += v * v;
            }
        }
        vs += __shfl_xor(vs, 16);
        vq += __shfl_xor(vq, 16);
        vs += __shfl_xor(vs, 32);
        vq += __shfl_xor(vq, 32);

        const float mu = vs * (1.0f / 128.0f);
        const float var = vq * (1.0f / 128.0f) - mu * mu;
        const float rstd = rsqrtf(var + 1e-5f);
        const float nmr = -mu * rstd;

        float* orow = out + (size_t)(rowbase + m) * D;
#pragma unroll
        for (int t = 0; t < 8; ++t) {
            const f32x4 gq = *(const f32x4*)&gms[t * 16 + q * 4];
            const f32x4 bq = *(const f32x4*)&bts[t * 16 + q * 4];
            float4 res;
            res.x = fmaf(fmaf(acc2[t][0], rstd, nmr), gq[0], bq[0]);
            res.y = fmaf(fmaf(acc2[t][1], rstd, nmr), gq[1], bq[1]);
            res.z = fmaf(fmaf(acc2[t][2], rstd, nmr), gq[2], bq[2]);
            res.w = fmaf(fmaf(acc2[t][3], rstd, nmr), gq[3], bq[3]);
            *(float4*)(orow + t * 16 + q * 4) = res;
        }
    }
}

extern "C" void kernel_launch(void* const* d_in, const int* in_sizes, int n_in,
                              void* d_out, int out_size, void* d_ws, size_t ws_size,
                              hipStream_t stream) {
    const float* x     = (const float*)d_in[0];
    const float* graph = (const float*)d_in[1];
    const float* W_msg = (const float*)d_in[2];
    const float* b_msg = (const float*)d_in[3];
    const float* W_upd = (const float*)d_in[4];
    const float* b_upd = (const float*)d_in[5];
    const float* W_out = (const float*)d_in[6];
    const float* b_out = (const float*)d_in[7];
    const float* gamma = (const float*)d_in[8];
    const float* beta  = (const float*)d_in[9];
    float* out = (float*)d_out;

    char* ws = (char*)d_ws;
    __bf16* W1s   = (__bf16*)(ws + 0);       // 32768 B (swizzled bf16 W_eff^T)
    __bf16* W2s   = (__bf16*)(ws + 32768);   // 32768 B (swizzled bf16 W_out^T)
    float*  G2    = (float*)(ws + 65536);    // 65536 B
    float*  b2tmp = (float*)(ws + 131072);   // 512 B
    float*  b_eff = (float*)(ws + 131584);   // 512 B

    prep1<<<16, 256, 0, stream>>>(W_msg, graph, b_msg, W_out, G2, b2tmp, W2s);
    prep2<<<16, 256, 0, stream>>>(W_upd, b_upd, G2, b2tmp, W1s, b_eff);
    fused_main<<<NROWS / 512, 512, 0, stream>>>(x, W1s, b_eff, b_out, gamma, beta, out);
}